// Round 3
// baseline (655.302 us; speedup 1.0000x reference)
//
#include <hip/hip_runtime.h>
#include <cstdint>
#include <cstddef>

typedef unsigned short u16;
typedef __attribute__((ext_vector_type(8))) short short8;
typedef __attribute__((ext_vector_type(4))) float f32x4;

#define T_SEQ 8192
#define NH 16
#define HD 128
#define NCH 64
#define KDIM 2048

constexpr float EPS = 1e-5f;
constexpr float SCALE = 0.08838834764831845f;   // 128^-0.5

__device__ __forceinline__ u16 f2bf(float f) {
  union { float f; unsigned u; } v; v.f = f;
  unsigned r = v.u + 0x7fffu + ((v.u >> 16) & 1u);
  return (u16)(r >> 16);
}
__device__ __forceinline__ float bf2f(u16 h) {
  union { unsigned u; float f; } v; v.u = ((unsigned)h) << 16;
  return v.f;
}
__device__ __forceinline__ unsigned pack2(u16 a, u16 b) {
  return (unsigned)a | ((unsigned)b << 16);
}
__device__ __forceinline__ f32x4 mfma16(short8 a, short8 b, f32x4 c) {
  return __builtin_amdgcn_mfma_f32_16x16x32_bf16(a, b, c, 0, 0, 0);
}
// async global->LDS, 16B per lane; LDS dest = wave-uniform base + lane*16B
__device__ __forceinline__ void gl2lds(const u16* g, u16* l) {
  __builtin_amdgcn_global_load_lds(
      (const __attribute__((address_space(1))) void*)g,
      (__attribute__((address_space(3))) void*)l, 16, 0, 0);
}

// ---------------- fp32 -> bf16 cast ----------------
__global__ __launch_bounds__(256) void cast_f32_bf16(const float* __restrict__ src,
                                                     u16* __restrict__ dst, long n) {
  long i = ((long)blockIdx.x * 256 + threadIdx.x) * 8;
  if (i >= n) return;
  float4 a = *(const float4*)(src + i);
  float4 b = *(const float4*)(src + i + 4);
  alignas(16) u16 u[8] = {f2bf(a.x), f2bf(a.y), f2bf(a.z), f2bf(a.w),
                          f2bf(b.x), f2bf(b.y), f2bf(b.z), f2bf(b.w)};
  *(int4*)(dst + i) = *(const int4*)u;
}

// ---------------- weight transpose+cast: W [K][N] fp32 -> Wt [N][K] bf16 ----
__global__ __launch_bounds__(256) void transpose_cast(const float* __restrict__ W,
                                                      u16* __restrict__ Wt, int K, int N) {
  __shared__ u16 tile[64][72];
  int n0 = blockIdx.x * 64, k0 = blockIdx.y * 64;
  int tx = threadIdx.x, ty = threadIdx.y; // (64,4)
  for (int r = ty; r < 64; r += 4)
    tile[r][tx] = f2bf(W[(size_t)(k0 + r) * N + n0 + tx]);
  __syncthreads();
  for (int r = ty; r < 64; r += 4)
    Wt[(size_t)(n0 + r) * K + k0 + tx] = tile[tx][r];
}

// ---------------- main GEMM: C = epi(A @ Bt^T), 256x256 tile, 8-phase ------
// Round-3 change: next-phase fragment ds_reads are issued AFTER this phase's
// lgkmcnt(0) and pinned before the MFMA cluster (sched_barrier), so the LDS
// pipe fills next-phase registers UNDER the current MFMA cluster. Only
// phase 1's 12 reads remain latency-exposed per K-tile.
template <int EPI>
__global__ __launch_bounds__(512) void gemm256(const u16* __restrict__ A,
                                               const u16* __restrict__ Bt, int N,
                                               float* __restrict__ Cf,
                                               u16* __restrict__ Cb,
                                               u16* __restrict__ q_t,
                                               u16* __restrict__ k_t,
                                               u16* __restrict__ v_t) {
  __shared__ u16 lds[65536];            // 131072 B
  const int tid  = threadIdx.x;
  const int wave = tid >> 6, lane = tid & 63;
  const int lr = lane & 15, lg = lane >> 4;
  const int wr = wave >> 2, wc = wave & 3;   // 2 x 4 wave grid
  const int bm = blockIdx.y, bn = blockIdx.x;
  const int sx  = (lr & 7) << 4;                    // read-side swizzle (bytes)
  const int cu0 = ((lg * 16) ^ sx) >> 1;            // k-slice 0 col (u16)
  const int cu1 = ((64 + lg * 16) ^ sx) >> 1;       // k-slice 1 col (u16)

  const int srow  = tid >> 3;
  const int sslot = (tid & 7) ^ (srow & 7);         // inverse swizzle on source
  const u16* gA = A  + (size_t)(bm * 256 + srow) * KDIM + sslot * 8;
  const u16* gB = Bt + (size_t)(bn * 256 + srow) * KDIM + sslot * 8;
  const int sbase = wave * 512;                     // u16; lane*8 u16 HW-implied

  f32x4 acc[8][4];
  #pragma unroll
  for (int i = 0; i < 8; i++)
    #pragma unroll
    for (int j = 0; j < 4; j++) acc[i][j] = (f32x4){0.f, 0.f, 0.f, 0.f};

  auto STAGE = [&](int op, int buf, int half, int kt) {
    const u16* g = (op ? gB : gA) + (size_t)half * 128 * KDIM + kt * 64;
    u16* l = &lds[buf * 32768 + op * 16384 + half * 8192 + sbase];
    gl2lds(g, l);
    gl2lds(g + (size_t)64 * KDIM, l + 4096);
  };

  const int aoff = (wr * 64 + lr) * 64;             // A: rows wr*64 + i*16 + lr
  const int boff = 16384 + (wc * 32 + lr) * 64;     // B: rows wc*32 + j*16 + lr

  // prologue: T0 {A0,B0,A1,B1} -> buf0; T1 {A0,B1,A1} -> buf1 (B0 comes in loop)
  STAGE(0, 0, 0, 0); STAGE(1, 0, 0, 0); STAGE(0, 0, 1, 0); STAGE(1, 0, 1, 0);
  STAGE(0, 1, 0, 1); STAGE(1, 1, 1, 1); STAGE(0, 1, 1, 1);
  asm volatile("s_waitcnt vmcnt(6)" ::: "memory");
  __builtin_amdgcn_s_barrier();

  short8 af0[4][2], af1[4][2], b0f[2][2], b1f[2][2];
  const int NT = KDIM / 64;                          // 32
  for (int t = 0; t < NT; ++t) {
    const int cur = t & 1, nxt = cur ^ 1;
    const int cb = cur * 32768;
    // ---------- phase 1: quadrant (m0, n0); prefetch T(t+1) B0 -> other buf
    #pragma unroll
    for (int i = 0; i < 4; i++) {
      af0[i][0] = *(const short8*)&lds[cb + aoff + i * 1024 + cu0];
      af0[i][1] = *(const short8*)&lds[cb + aoff + i * 1024 + cu1];
    }
    #pragma unroll
    for (int j = 0; j < 2; j++) {
      b0f[j][0] = *(const short8*)&lds[cb + boff + j * 1024 + cu0];
      b0f[j][1] = *(const short8*)&lds[cb + boff + j * 1024 + cu1];
    }
    if (t + 1 < NT) STAGE(1, nxt, 0, t + 1);
    __builtin_amdgcn_s_barrier();
    asm volatile("s_waitcnt lgkmcnt(0)" ::: "memory");
    // issue phase-2's b1 reads now; they complete under the MFMA cluster
    #pragma unroll
    for (int j = 0; j < 2; j++) {
      b1f[j][0] = *(const short8*)&lds[cb + 8192 + boff + j * 1024 + cu0];
      b1f[j][1] = *(const short8*)&lds[cb + 8192 + boff + j * 1024 + cu1];
    }
    __builtin_amdgcn_sched_barrier(0);
    __builtin_amdgcn_s_setprio(1);
    #pragma unroll
    for (int i = 0; i < 4; i++)
      #pragma unroll
      for (int j = 0; j < 2; j++) {
        acc[i][j] = mfma16(af0[i][0], b0f[j][0], acc[i][j]);
        acc[i][j] = mfma16(af0[i][1], b0f[j][1], acc[i][j]);
      }
    __builtin_amdgcn_s_setprio(0);
    __builtin_amdgcn_s_barrier();
    // ---------- phase 2: (m0, n1); prefetch T(t+2) A0 -> cur
    if (t + 2 < NT) STAGE(0, cur, 0, t + 2);
    __builtin_amdgcn_s_barrier();
    asm volatile("s_waitcnt lgkmcnt(0)" ::: "memory");
    // issue phase-3/4's A-frags (m1) now; complete under this MFMA cluster
    #pragma unroll
    for (int i = 0; i < 4; i++) {
      af1[i][0] = *(const short8*)&lds[cb + 8192 + aoff + i * 1024 + cu0];
      af1[i][1] = *(const short8*)&lds[cb + 8192 + aoff + i * 1024 + cu1];
    }
    __builtin_amdgcn_sched_barrier(0);
    __builtin_amdgcn_s_setprio(1);
    #pragma unroll
    for (int i = 0; i < 4; i++)
      #pragma unroll
      for (int j = 0; j < 2; j++) {
        acc[i][2 + j] = mfma16(af0[i][0], b1f[j][0], acc[i][2 + j]);
        acc[i][2 + j] = mfma16(af0[i][1], b1f[j][1], acc[i][2 + j]);
      }
    __builtin_amdgcn_s_setprio(0);
    __builtin_amdgcn_s_barrier();
    // ---------- phase 3: (m1, n1); prefetch T(t+2) B1 -> cur
    if (t + 2 < NT) STAGE(1, cur, 1, t + 2);
    __builtin_amdgcn_s_barrier();
    asm volatile("s_waitcnt lgkmcnt(0)" ::: "memory");
    __builtin_amdgcn_s_setprio(1);
    #pragma unroll
    for (int i = 0; i < 4; i++)
      #pragma unroll
      for (int j = 0; j < 2; j++) {
        acc[4 + i][2 + j] = mfma16(af1[i][0], b1f[j][0], acc[4 + i][2 + j]);
        acc[4 + i][2 + j] = mfma16(af1[i][1], b1f[j][1], acc[4 + i][2 + j]);
      }
    __builtin_amdgcn_s_setprio(0);
    __builtin_amdgcn_s_barrier();
    // ---------- phase 4: (m1, n0) [regs only]; prefetch T(t+2) A1 -> cur
    if (t + 2 < NT) STAGE(0, cur, 1, t + 2);
    __builtin_amdgcn_s_barrier();
    asm volatile("s_waitcnt lgkmcnt(0)" ::: "memory");
    __builtin_amdgcn_s_setprio(1);
    #pragma unroll
    for (int i = 0; i < 4; i++)
      #pragma unroll
      for (int j = 0; j < 2; j++) {
        acc[4 + i][j] = mfma16(af1[i][0], b0f[j][0], acc[4 + i][j]);
        acc[4 + i][j] = mfma16(af1[i][1], b0f[j][1], acc[4 + i][j]);
      }
    __builtin_amdgcn_s_setprio(0);
    if (t + 2 < NT) asm volatile("s_waitcnt vmcnt(6)" ::: "memory");
    else            asm volatile("s_waitcnt vmcnt(0)" ::: "memory");
    __builtin_amdgcn_s_barrier();
  }

  #pragma unroll
  for (int mi = 0; mi < 8; mi++)
    #pragma unroll
    for (int nj = 0; nj < 4; nj++)
      #pragma unroll
      for (int r = 0; r < 4; r++) {
        int row = bm * 256 + (mi >> 2) * 128 + wr * 64 + (mi & 3) * 16 + lg * 4 + r;
        int col = bn * 256 + (nj >> 1) * 128 + wc * 32 + (nj & 1) * 16 + lr;
        float v = acc[mi][nj][r];
        if (EPI == 0) {
          Cf[(size_t)row * N + col] = v;
        } else if (EPI == 1) {
          Cb[(size_t)row * N + col] = f2bf(v);
        } else {
          float s = v / (1.0f + __expf(-v));   // silu
          int part = col >> 11;
          int h = (col >> 7) & 15;
          int d = col & 127;
          u16* dst = part == 0 ? q_t : (part == 1 ? k_t : v_t);
          dst[((size_t)h * T_SEQ + row) * HD + d] = f2bf(s);
        }
      }
}

// ---------------- per-(t,h) RMSNorm + RoPE, one wave per row ----------------
__global__ __launch_bounds__(256) void qk_prep(u16* __restrict__ q_t, u16* __restrict__ k_t,
                                               const int* __restrict__ positions,
                                               const float* __restrict__ q_ln_w,
                                               const float* __restrict__ k_ln_w) {
  const int t = blockIdx.x;
  const int h = blockIdx.y * 4 + (threadIdx.x >> 6);
  const int lane = threadIdx.x & 63;
  const int d0 = lane * 2;
  const size_t base = ((size_t)h * T_SEQ + t) * HD + d0;
  unsigned qu = *(const unsigned*)(q_t + base);
  unsigned ku = *(const unsigned*)(k_t + base);
  float q0 = bf2f((u16)qu), q1 = bf2f((u16)(qu >> 16));
  float k0 = bf2f((u16)ku), k1 = bf2f((u16)(ku >> 16));
  float s1 = q0 * q0 + q1 * q1;
  float s2 = k0 * k0 + k1 * k1;
  #pragma unroll
  for (int off = 32; off > 0; off >>= 1) {
    s1 += __shfl_xor(s1, off);
    s2 += __shfl_xor(s2, off);
  }
  float rq = rsqrtf(s1 * (1.0f / 128.0f) + EPS);
  float rk = rsqrtf(s2 * (1.0f / 128.0f) + EPS);
  float w0 = q_ln_w[d0], w1 = q_ln_w[d0 + 1];
  float u0 = k_ln_w[d0], u1 = k_ln_w[d0 + 1];
  float qn0 = q0 * rq * w0, qn1 = q1 * rq * w1;
  float kn0 = k0 * rk * u0, kn1 = k1 * rk * u1;
  // partners (d ^ 64)
  float qp0 = __shfl_xor(qn0, 32), qp1 = __shfl_xor(qn1, 32);
  float kp0 = __shfl_xor(kn0, 32), kp1 = __shfl_xor(kn1, 32);
  int i0 = d0 & 63;
  // 1/ROPE_BASE^(i/64) = 2^(-i*log2(6e5)/64); log2(600000)=19.194593
  float invf0 = exp2f((float)i0 * (-19.194593f / 64.0f));
  float invf1 = exp2f((float)(i0 + 1) * (-19.194593f / 64.0f));
  float pos = (float)positions[t];
  float a0 = pos * invf0, a1 = pos * invf1;
  float c0 = cosf(a0), sn0 = sinf(a0), c1 = cosf(a1), sn1 = sinf(a1);
  bool lo = lane < 32;
  float qr0 = lo ? (qn0 * c0 - qp0 * sn0) : (qn0 * c0 + qp0 * sn0);
  float qr1 = lo ? (qn1 * c1 - qp1 * sn1) : (qn1 * c1 + qp1 * sn1);
  float kr0 = lo ? (kn0 * c0 - kp0 * sn0) : (kn0 * c0 + kp0 * sn0);
  float kr1 = lo ? (kn1 * c1 - kp1 * sn1) : (kn1 * c1 + kp1 * sn1);
  *(unsigned*)(q_t + base) = pack2(f2bf(qr0 * SCALE), f2bf(qr1 * SCALE));
  *(unsigned*)(k_t + base) = pack2(f2bf(kr0), f2bf(kr1));
}

// ---------------- phase B: G[h][c][e][d] = sum_{t in chunk} V[t][e] K[t][d] ----
__global__ __launch_bounds__(256) void attn_phaseB(const u16* __restrict__ k_t,
                                                   const u16* __restrict__ v_t,
                                                   u16* __restrict__ G) {
  const int c = blockIdx.x, h = blockIdx.y;
  __shared__ u16 lV[128 * 72];
  __shared__ u16 lK[128 * 72];
  const int tid = threadIdx.x, wave = tid >> 6, lane = tid & 63;
  const int wm = (wave >> 1) * 64, wn = (wave & 1) * 64;
  const int lr = lane & 15, lg = lane >> 4;
  f32x4 acc[4][4];
  #pragma unroll
  for (int i = 0; i < 4; i++)
    #pragma unroll
    for (int j = 0; j < 4; j++) acc[i][j] = (f32x4){0.f, 0.f, 0.f, 0.f};

  const int t0 = (tid >> 4) * 4;            // 0..60, 4 rows per thread
  const int ds = (tid & 15) * 8;            // d-segment of 8
  for (int h2 = 0; h2 < 2; h2++) {
    __syncthreads();
    const u16* vsrc = v_t + ((size_t)h * T_SEQ + c * 128 + h2 * 64 + t0) * HD + ds;
    const u16* ksrc = k_t + ((size_t)h * T_SEQ + c * 128 + h2 * 64 + t0) * HD + ds;
    int4 rv[4], rk[4];
    #pragma unroll
    for (int r = 0; r < 4; r++) {
      rv[r] = *(const int4*)(vsrc + r * HD);
      rk[r] = *(const int4*)(ksrc + r * HD);
    }
    const u16* v0 = (const u16*)&rv[0]; const u16* v1 = (const u16*)&rv[1];
    const u16* v2 = (const u16*)&rv[2]; const u16* v3 = (const u16*)&rv[3];
    const u16* K0 = (const u16*)&rk[0]; const u16* K1 = (const u16*)&rk[1];
    const u16* K2 = (const u16*)&rk[2]; const u16* K3 = (const u16*)&rk[3];
    #pragma unroll
    for (int j = 0; j < 8; j++) {
      uint2 wv, wk;
      wv.x = pack2(v0[j], v1[j]); wv.y = pack2(v2[j], v3[j]);
      wk.x = pack2(K0[j], K1[j]); wk.y = pack2(K2[j], K3[j]);
      *(uint2*)&lV[(ds + j) * 72 + t0] = wv;
      *(uint2*)&lK[(ds + j) * 72 + t0] = wk;
    }
    __syncthreads();
    #pragma unroll
    for (int kk = 0; kk < 64; kk += 32) {
      short8 af[4], bfr[4];
      #pragma unroll
      for (int i = 0; i < 4; i++)
        af[i] = *(const short8*)&lV[(wm + i * 16 + lr) * 72 + kk + lg * 8];
      #pragma unroll
      for (int j = 0; j < 4; j++)
        bfr[j] = *(const short8*)&lK[(wn + j * 16 + lr) * 72 + kk + lg * 8];
      #pragma unroll
      for (int i = 0; i < 4; i++)
        #pragma unroll
        for (int j = 0; j < 4; j++)
          acc[i][j] = mfma16(af[i], bfr[j], acc[i][j]);
    }
  }
  u16* Gp = G + ((size_t)h * NCH + c) * 16384;
  #pragma unroll
  for (int i = 0; i < 4; i++)
    #pragma unroll
    for (int j = 0; j < 4; j++)
      #pragma unroll
      for (int r = 0; r < 4; r++)
        Gp[(wm + i * 16 + lg * 4 + r) * 128 + wn + j * 16 + lr] = f2bf(acc[i][j][r]);
}

// exclusive prefix over chunk axis, bf16 storage / fp32 accumulator, in place
__global__ __launch_bounds__(256) void prefix_S(u16* __restrict__ G) {
  int idx = blockIdx.x * 256 + threadIdx.x;   // 65536 threads over 16*4096 quads
  int h = idx >> 12;
  int e4 = (idx & 4095) * 4;
  float run0 = 0.f, run1 = 0.f, run2 = 0.f, run3 = 0.f;
  size_t base = (size_t)h * NCH * 16384 + e4;
  for (int c = 0; c < NCH; c++) {
    uint2 g = *(uint2*)&G[base + (size_t)c * 16384];
    float a0 = bf2f((u16)g.x), a1 = bf2f((u16)(g.x >> 16));
    float a2 = bf2f((u16)g.y), a3 = bf2f((u16)(g.y >> 16));
    uint2 o;
    o.x = pack2(f2bf(run0), f2bf(run1));
    o.y = pack2(f2bf(run2), f2bf(run3));
    *(uint2*)&G[base + (size_t)c * 16384] = o;
    run0 += a0; run1 += a1; run2 += a2; run3 += a3;
  }
}

// ---------------- phase C: O = tril(Q K^T) V + Q S ----------------
// writes O head-major IN PLACE into the G tile this block consumed
__global__ __launch_bounds__(256) void attn_phaseC(const u16* __restrict__ q_t,
                                                   const u16* __restrict__ k_t,
                                                   const u16* __restrict__ v_t,
                                                   const u16* __restrict__ G,
                                                   u16* __restrict__ o_hm) {
  const int c = blockIdx.x, h = blockIdx.y;
  __shared__ u16 lP[128 * 136];
  __shared__ u16 lV[128 * 72];
  const int tid = threadIdx.x, wave = tid >> 6, lane = tid & 63;
  const int wm = wave * 32;          // 4x1 wave layout, 32 rows each
  const int lr = lane & 15, lg = lane >> 4;

  f32x4 acc1[2][8], acc2[2][8];
  #pragma unroll
  for (int i = 0; i < 2; i++)
    #pragma unroll
    for (int j = 0; j < 8; j++) {
      acc1[i][j] = (f32x4){0.f, 0.f, 0.f, 0.f};
      acc2[i][j] = (f32x4){0.f, 0.f, 0.f, 0.f};
    }

  const u16* Sp = G + ((size_t)h * NCH + c) * 16384;
  const u16* qbase = q_t + ((size_t)h * T_SEQ + c * 128) * HD;
  const u16* kbase = k_t + ((size_t)h * T_SEQ + c * 128) * HD;

  #pragma unroll
  for (int kk = 0; kk < 128; kk += 32) {
    short8 af[2];
    #pragma unroll
    for (int i = 0; i < 2; i++)
      af[i] = *(const short8*)(qbase + (wm + i * 16 + lr) * HD + kk + lg * 8);
    #pragma unroll
    for (int j = 0; j < 8; j++) {
      short8 bK = *(const short8*)(kbase + (j * 16 + lr) * HD + kk + lg * 8);
      short8 bS = *(const short8*)(Sp + (j * 16 + lr) * 128 + kk + lg * 8);
      #pragma unroll
      for (int i = 0; i < 2; i++) {
        acc1[i][j] = mfma16(af[i], bK, acc1[i][j]);   // scores
        acc2[i][j] = mfma16(af[i], bS, acc2[i][j]);   // Q @ S
      }
    }
  }
  // mask scores (tril) and park P in LDS (bf16, row-major over s)
  #pragma unroll
  for (int i = 0; i < 2; i++)
    #pragma unroll
    for (int j = 0; j < 8; j++)
      #pragma unroll
      for (int r = 0; r < 4; r++) {
        int row = wm + i * 16 + lg * 4 + r;
        int col = j * 16 + lr;
        float v = (col <= row) ? acc1[i][j][r] : 0.0f;
        lP[row * 136 + col] = f2bf(v);
      }

  const int t0 = (tid >> 4) * 4;            // register-transpose staging for V
  const int ds = (tid & 15) * 8;
  for (int sh2 = 0; sh2 < 2; sh2++) {
    __syncthreads();
    const u16* vsrc = v_t + ((size_t)h * T_SEQ + c * 128 + sh2 * 64 + t0) * HD + ds;
    int4 rv[4];
    #pragma unroll
    for (int r = 0; r < 4; r++) rv[r] = *(const int4*)(vsrc + r * HD);
    const u16* v0 = (const u16*)&rv[0]; const u16* v1 = (const u16*)&rv[1];
    const u16* v2 = (const u16*)&rv[2]; const u16* v3 = (const u16*)&rv[3];
    #pragma unroll
    for (int j = 0; j < 8; j++) {
      uint2 wv;
      wv.x = pack2(v0[j], v1[j]); wv.y = pack2(v2[j], v3[j]);
      *(uint2*)&lV[(ds + j) * 72 + t0] = wv;
    }
    __syncthreads();
    #pragma unroll
    for (int kk = 0; kk < 64; kk += 32) {
      short8 af[2];
      #pragma unroll
      for (int i = 0; i < 2; i++)
        af[i] = *(const short8*)&lP[(wm + i * 16 + lr) * 136 + sh2 * 64 + kk + lg * 8];
      #pragma unroll
      for (int j = 0; j < 8; j++) {
        short8 bV = *(const short8*)&lV[(j * 16 + lr) * 72 + kk + lg * 8];
        #pragma unroll
        for (int i = 0; i < 2; i++)
          acc2[i][j] = mfma16(af[i], bV, acc2[i][j]);
      }
    }
  }
  u16* op = o_hm + ((size_t)h * NCH + c) * 16384;
  #pragma unroll
  for (int i = 0; i < 2; i++)
    #pragma unroll
    for (int j = 0; j < 8; j++)
      #pragma unroll
      for (int r = 0; r < 4; r++) {
        int row = wm + i * 16 + lg * 4 + r;
        int e = j * 16 + lr;
        op[row * 128 + e] = f2bf(acc2[i][j][r]);
      }
}

// ---------------- gated rmsnorm: gated = sigmoid(gate) * rmsnorm(o) ----------------
__global__ __launch_bounds__(256) void gated_kernel(const u16* __restrict__ o_hm,
                                                    const u16* __restrict__ gate_bf,
                                                    const float* __restrict__ g_norm_w,
                                                    u16* __restrict__ gated_bf) {
  const int t = blockIdx.x, tid = threadIdx.x;
  const int h = tid >> 4, e0 = (tid & 15) * 8;
  const int c = t >> 7, row = t & 127;
  short8 ov = *(const short8*)(o_hm + (((size_t)h * NCH + c) * 128 + row) * 128 + e0);
  const u16* ovp = (const u16*)&ov;
  float vals[8], ss = 0.f;
  #pragma unroll
  for (int j = 0; j < 8; j++) {
    float v = bf2f(ovp[j]);
    vals[j] = v;
    ss += v * v;
  }
  #pragma unroll
  for (int off = 32; off > 0; off >>= 1) ss += __shfl_xor(ss, off);
  __shared__ float sh[4];
  if ((tid & 63) == 0) sh[tid >> 6] = ss;
  __syncthreads();
  ss = sh[0] + sh[1] + sh[2] + sh[3];
  float r = rsqrtf(ss * (1.0f / 2048.0f) + EPS);
  short8 gv = *(const short8*)(gate_bf + (size_t)t * 2048 + tid * 8);
  const u16* gvp = (const u16*)&gv;
  float4 w0 = *(const float4*)(g_norm_w + tid * 8);
  float4 w1 = *(const float4*)(g_norm_w + tid * 8 + 4);
  float wv[8] = {w0.x, w0.y, w0.z, w0.w, w1.x, w1.y, w1.z, w1.w};
  alignas(16) u16 outu[8];
  #pragma unroll
  for (int j = 0; j < 8; j++) {
    float normed = vals[j] * r * wv[j];
    float g = bf2f(gvp[j]);
    float sg = 1.0f / (1.0f + __expf(-g));
    outu[j] = f2bf(normed * sg);
  }
  *(int4*)(gated_bf + (size_t)t * 2048 + tid * 8) = *(const int4*)outu;
}

// ---------------- launch ----------------
extern "C" void kernel_launch(void* const* d_in, const int* in_sizes, int n_in,
                              void* d_out, int out_size, void* d_ws, size_t ws_size,
                              hipStream_t stream) {
  const float* x = (const float*)d_in[0];
  const int* positions = (const int*)d_in[1];
  const float* Wqkv = (const float*)d_in[2];
  const float* q_ln_w = (const float*)d_in[3];
  const float* k_ln_w = (const float*)d_in[4];
  const float* Wg = (const float*)d_in[5];
  const float* g_norm_w = (const float*)d_in[6];
  const float* Wo = (const float*)d_in[7];
  float* out = (float*)d_out;

  // Regions (32 MiB each unless noted), aliased by lifetime:
  //  R0 [0,32M):      WqkvT(25.2M) -> G -> o_hm (in-place per-block)
  //  R1 [32M,40M):    WgT (8M)
  //  R2 [40M,72M):    q_t -> gated
  //  R3 [72M,104M):   k_t -> gate_bf
  //  R4 [104M,136M):  v_t -> WoT (8M)
  //  R5 [136M,168M):  x_bf (alive the whole pipeline; no recast)
  char* ws = (char*)d_ws;
  const size_t M32 = (size_t)32 * 1024 * 1024;
  u16* WqkvT   = (u16*)ws;
  u16* G       = (u16*)ws;
  u16* WgT     = (u16*)(ws + M32);
  u16* q_t     = (u16*)(ws + M32 + 8388608);
  u16* gated   = q_t;
  u16* k_t     = (u16*)(ws + M32 + 8388608 + M32);
  u16* gate_bf = k_t;
  u16* v_t     = (u16*)(ws + M32 + 8388608 + 2 * M32);
  u16* WoT     = v_t;
  u16* x_bf    = (u16*)(ws + M32 + 8388608 + 3 * M32);
  const size_t needed = M32 + 8388608 + 4 * M32;   // 176,160,768
  if (ws_size < needed) return;

  cast_f32_bf16<<<8192, 256, 0, stream>>>(x, x_bf, (long)8192 * 2048);
  transpose_cast<<<dim3(96, 32), dim3(64, 4), 0, stream>>>(Wqkv, WqkvT, 2048, 6144);
  transpose_cast<<<dim3(32, 32), dim3(64, 4), 0, stream>>>(Wg, WgT, 2048, 2048);

  gemm256<2><<<dim3(24, 32), 512, 0, stream>>>(x_bf, WqkvT, 6144, nullptr, nullptr, q_t, k_t, v_t);

  qk_prep<<<dim3(8192, 4), 256, 0, stream>>>(q_t, k_t, positions, q_ln_w, k_ln_w);

  attn_phaseB<<<dim3(64, 16), 256, 0, stream>>>(k_t, v_t, G);
  prefix_S<<<256, 256, 0, stream>>>(G);
  attn_phaseC<<<dim3(64, 16), 256, 0, stream>>>(q_t, k_t, v_t, G, /*o_hm=*/G);

  // x_bf still alive -> gate GEMM directly (no recast); gate_bf overlays dead k_t
  gemm256<1><<<dim3(8, 32), 512, 0, stream>>>(x_bf, WgT, 2048, nullptr, gate_bf, nullptr, nullptr, nullptr);
  gated_kernel<<<8192, 256, 0, stream>>>(G, gate_bf, g_norm_w, gated);

  transpose_cast<<<dim3(32, 32), dim3(64, 4), 0, stream>>>(Wo, WoT, 2048, 2048);
  gemm256<0><<<dim3(8, 32), 512, 0, stream>>>(gated, WoT, 2048, out, nullptr, nullptr, nullptr, nullptr);
}

// Round 4
// 634.011 us; speedup vs baseline: 1.0336x; 1.0336x over previous
//
#include <hip/hip_runtime.h>
#include <cstdint>
#include <cstddef>

typedef unsigned short u16;
typedef __attribute__((ext_vector_type(8))) short short8;
typedef __attribute__((ext_vector_type(4))) float f32x4;

#define T_SEQ 8192
#define NH 16
#define HD 128
#define NCH 64
#define KDIM 2048

constexpr float EPS = 1e-5f;
constexpr float SCALE = 0.08838834764831845f;   // 128^-0.5

__device__ __forceinline__ u16 f2bf(float f) {
  union { float f; unsigned u; } v; v.f = f;
  unsigned r = v.u + 0x7fffu + ((v.u >> 16) & 1u);
  return (u16)(r >> 16);
}
__device__ __forceinline__ float bf2f(u16 h) {
  union { unsigned u; float f; } v; v.u = ((unsigned)h) << 16;
  return v.f;
}
__device__ __forceinline__ unsigned pack2(u16 a, u16 b) {
  return (unsigned)a | ((unsigned)b << 16);
}
__device__ __forceinline__ f32x4 mfma16(short8 a, short8 b, f32x4 c) {
  return __builtin_amdgcn_mfma_f32_16x16x32_bf16(a, b, c, 0, 0, 0);
}
// async global->LDS, 16B per lane; LDS dest = wave-uniform base + lane*16B
__device__ __forceinline__ void gl2lds(const u16* g, u16* l) {
  __builtin_amdgcn_global_load_lds(
      (const __attribute__((address_space(1))) void*)g,
      (__attribute__((address_space(3))) void*)l, 16, 0, 0);
}

// ---------------- fp32 -> bf16 cast ----------------
__global__ __launch_bounds__(256) void cast_f32_bf16(const float* __restrict__ src,
                                                     u16* __restrict__ dst, long n) {
  long i = ((long)blockIdx.x * 256 + threadIdx.x) * 8;
  if (i >= n) return;
  float4 a = *(const float4*)(src + i);
  float4 b = *(const float4*)(src + i + 4);
  alignas(16) u16 u[8] = {f2bf(a.x), f2bf(a.y), f2bf(a.z), f2bf(a.w),
                          f2bf(b.x), f2bf(b.y), f2bf(b.z), f2bf(b.w)};
  *(int4*)(dst + i) = *(const int4*)u;
}

// ---------------- weight transpose+cast: W [K][N] fp32 -> Wt [N][K] bf16 ----
__global__ __launch_bounds__(256) void transpose_cast(const float* __restrict__ W,
                                                      u16* __restrict__ Wt, int K, int N) {
  __shared__ u16 tile[64][72];
  int n0 = blockIdx.x * 64, k0 = blockIdx.y * 64;
  int tx = threadIdx.x, ty = threadIdx.y; // (64,4)
  for (int r = ty; r < 64; r += 4)
    tile[r][tx] = f2bf(W[(size_t)(k0 + r) * N + n0 + tx]);
  __syncthreads();
  for (int r = ty; r < 64; r += 4)
    Wt[(size_t)(n0 + r) * K + k0 + tx] = tile[tx][r];
}

// ---------------- main GEMM: C = epi(A @ Bt^T), 256x256 tile, 8-phase ------
// Round-4 change: XCD-chunked blockIdx swizzle (T1). Consecutive logical
// tiles (sharing A/B panels) land on the SAME XCD's L2: chunk working set
// (4 A-panels + 24 B-panels)*32KB = 896KB < 4MB L2. Schedule = round-2's
// (best measured; round-3 reorder reverted).
template <int EPI>
__global__ __launch_bounds__(512) void gemm256(const u16* __restrict__ A,
                                               const u16* __restrict__ Bt, int N,
                                               float* __restrict__ Cf,
                                               u16* __restrict__ Cb,
                                               u16* __restrict__ q_t,
                                               u16* __restrict__ k_t,
                                               u16* __restrict__ v_t) {
  __shared__ u16 lds[65536];            // 131072 B
  const int tid  = threadIdx.x;
  const int wave = tid >> 6, lane = tid & 63;
  const int lr = lane & 15, lg = lane >> 4;
  const int wr = wave >> 2, wc = wave & 3;   // 2 x 4 wave grid
  // ---- XCD-chunked swizzle (bijective: nwg % 8 == 0 for all our grids) ----
  const int nx = gridDim.x;
  const int nwg = nx * gridDim.y;
  const int flat = blockIdx.y * nx + blockIdx.x;
  const int logical = (flat & 7) * (nwg >> 3) + (flat >> 3);
  const int bm = logical / nx, bn = logical % nx;
  const int sx  = (lr & 7) << 4;                    // read-side swizzle (bytes)
  const int cu0 = ((lg * 16) ^ sx) >> 1;            // k-slice 0 col (u16)
  const int cu1 = ((64 + lg * 16) ^ sx) >> 1;       // k-slice 1 col (u16)

  const int srow  = tid >> 3;
  const int sslot = (tid & 7) ^ (srow & 7);         // inverse swizzle on source
  const u16* gA = A  + (size_t)(bm * 256 + srow) * KDIM + sslot * 8;
  const u16* gB = Bt + (size_t)(bn * 256 + srow) * KDIM + sslot * 8;
  const int sbase = wave * 512;                     // u16; lane*8 u16 HW-implied

  f32x4 acc[8][4];
  #pragma unroll
  for (int i = 0; i < 8; i++)
    #pragma unroll
    for (int j = 0; j < 4; j++) acc[i][j] = (f32x4){0.f, 0.f, 0.f, 0.f};

  auto STAGE = [&](int op, int buf, int half, int kt) {
    const u16* g = (op ? gB : gA) + (size_t)half * 128 * KDIM + kt * 64;
    u16* l = &lds[buf * 32768 + op * 16384 + half * 8192 + sbase];
    gl2lds(g, l);
    gl2lds(g + (size_t)64 * KDIM, l + 4096);
  };

  const int aoff = (wr * 64 + lr) * 64;             // A: rows wr*64 + i*16 + lr
  const int boff = 16384 + (wc * 32 + lr) * 64;     // B: rows wc*32 + j*16 + lr

  // prologue: T0 {A0,B0,A1,B1} -> buf0; T1 {A0,B1,A1} -> buf1 (B0 comes in loop)
  STAGE(0, 0, 0, 0); STAGE(1, 0, 0, 0); STAGE(0, 0, 1, 0); STAGE(1, 0, 1, 0);
  STAGE(0, 1, 0, 1); STAGE(1, 1, 1, 1); STAGE(0, 1, 1, 1);
  asm volatile("s_waitcnt vmcnt(6)" ::: "memory");
  __builtin_amdgcn_s_barrier();

  short8 af[4][2], b0f[2][2], b1f[2][2];
  const int NT = KDIM / 64;                          // 32
  for (int t = 0; t < NT; ++t) {
    const int cur = t & 1, nxt = cur ^ 1;
    const int cb = cur * 32768;
    // ---------- phase 1: quadrant (m0, n0); prefetch T(t+1) B0 -> other buf
    #pragma unroll
    for (int i = 0; i < 4; i++) {
      af[i][0] = *(const short8*)&lds[cb + aoff + i * 1024 + cu0];
      af[i][1] = *(const short8*)&lds[cb + aoff + i * 1024 + cu1];
    }
    #pragma unroll
    for (int j = 0; j < 2; j++) {
      b0f[j][0] = *(const short8*)&lds[cb + boff + j * 1024 + cu0];
      b0f[j][1] = *(const short8*)&lds[cb + boff + j * 1024 + cu1];
    }
    if (t + 1 < NT) STAGE(1, nxt, 0, t + 1);
    __builtin_amdgcn_s_barrier();
    asm volatile("s_waitcnt lgkmcnt(0)" ::: "memory");
    __builtin_amdgcn_s_setprio(1);
    #pragma unroll
    for (int i = 0; i < 4; i++)
      #pragma unroll
      for (int j = 0; j < 2; j++) {
        acc[i][j] = mfma16(af[i][0], b0f[j][0], acc[i][j]);
        acc[i][j] = mfma16(af[i][1], b0f[j][1], acc[i][j]);
      }
    __builtin_amdgcn_s_setprio(0);
    __builtin_amdgcn_s_barrier();
    // ---------- phase 2: (m0, n1); prefetch T(t+2) A0 -> cur
    #pragma unroll
    for (int j = 0; j < 2; j++) {
      b1f[j][0] = *(const short8*)&lds[cb + 8192 + boff + j * 1024 + cu0];
      b1f[j][1] = *(const short8*)&lds[cb + 8192 + boff + j * 1024 + cu1];
    }
    if (t + 2 < NT) STAGE(0, cur, 0, t + 2);
    __builtin_amdgcn_s_barrier();
    asm volatile("s_waitcnt lgkmcnt(0)" ::: "memory");
    __builtin_amdgcn_s_setprio(1);
    #pragma unroll
    for (int i = 0; i < 4; i++)
      #pragma unroll
      for (int j = 0; j < 2; j++) {
        acc[i][2 + j] = mfma16(af[i][0], b1f[j][0], acc[i][2 + j]);
        acc[i][2 + j] = mfma16(af[i][1], b1f[j][1], acc[i][2 + j]);
      }
    __builtin_amdgcn_s_setprio(0);
    __builtin_amdgcn_s_barrier();
    // ---------- phase 3: (m1, n1); prefetch T(t+2) B1 -> cur
    #pragma unroll
    for (int i = 0; i < 4; i++) {
      af[i][0] = *(const short8*)&lds[cb + 8192 + aoff + i * 1024 + cu0];
      af[i][1] = *(const short8*)&lds[cb + 8192 + aoff + i * 1024 + cu1];
    }
    if (t + 2 < NT) STAGE(1, cur, 1, t + 2);
    __builtin_amdgcn_s_barrier();
    asm volatile("s_waitcnt lgkmcnt(0)" ::: "memory");
    __builtin_amdgcn_s_setprio(1);
    #pragma unroll
    for (int i = 0; i < 4; i++)
      #pragma unroll
      for (int j = 0; j < 2; j++) {
        acc[4 + i][2 + j] = mfma16(af[i][0], b1f[j][0], acc[4 + i][2 + j]);
        acc[4 + i][2 + j] = mfma16(af[i][1], b1f[j][1], acc[4 + i][2 + j]);
      }
    __builtin_amdgcn_s_setprio(0);
    __builtin_amdgcn_s_barrier();
    // ---------- phase 4: (m1, n0) [regs only]; prefetch T(t+2) A1 -> cur
    if (t + 2 < NT) STAGE(0, cur, 1, t + 2);
    __builtin_amdgcn_s_barrier();
    asm volatile("s_waitcnt lgkmcnt(0)" ::: "memory");
    __builtin_amdgcn_s_setprio(1);
    #pragma unroll
    for (int i = 0; i < 4; i++)
      #pragma unroll
      for (int j = 0; j < 2; j++) {
        acc[4 + i][j] = mfma16(af[i][0], b0f[j][0], acc[4 + i][j]);
        acc[4 + i][j] = mfma16(af[i][1], b0f[j][1], acc[4 + i][j]);
      }
    __builtin_amdgcn_s_setprio(0);
    if (t + 2 < NT) asm volatile("s_waitcnt vmcnt(6)" ::: "memory");
    else            asm volatile("s_waitcnt vmcnt(0)" ::: "memory");
    __builtin_amdgcn_s_barrier();
  }

  #pragma unroll
  for (int mi = 0; mi < 8; mi++)
    #pragma unroll
    for (int nj = 0; nj < 4; nj++)
      #pragma unroll
      for (int r = 0; r < 4; r++) {
        int row = bm * 256 + (mi >> 2) * 128 + wr * 64 + (mi & 3) * 16 + lg * 4 + r;
        int col = bn * 256 + (nj >> 1) * 128 + wc * 32 + (nj & 1) * 16 + lr;
        float v = acc[mi][nj][r];
        if (EPI == 0) {
          Cf[(size_t)row * N + col] = v;
        } else if (EPI == 1) {
          Cb[(size_t)row * N + col] = f2bf(v);
        } else {
          float s = v / (1.0f + __expf(-v));   // silu
          int part = col >> 11;
          int h = (col >> 7) & 15;
          int d = col & 127;
          u16* dst = part == 0 ? q_t : (part == 1 ? k_t : v_t);
          dst[((size_t)h * T_SEQ + row) * HD + d] = f2bf(s);
        }
      }
}

// ---------------- per-(t,h) RMSNorm + RoPE, one wave per row ----------------
__global__ __launch_bounds__(256) void qk_prep(u16* __restrict__ q_t, u16* __restrict__ k_t,
                                               const int* __restrict__ positions,
                                               const float* __restrict__ q_ln_w,
                                               const float* __restrict__ k_ln_w) {
  const int t = blockIdx.x;
  const int h = blockIdx.y * 4 + (threadIdx.x >> 6);
  const int lane = threadIdx.x & 63;
  const int d0 = lane * 2;
  const size_t base = ((size_t)h * T_SEQ + t) * HD + d0;
  unsigned qu = *(const unsigned*)(q_t + base);
  unsigned ku = *(const unsigned*)(k_t + base);
  float q0 = bf2f((u16)qu), q1 = bf2f((u16)(qu >> 16));
  float k0 = bf2f((u16)ku), k1 = bf2f((u16)(ku >> 16));
  float s1 = q0 * q0 + q1 * q1;
  float s2 = k0 * k0 + k1 * k1;
  #pragma unroll
  for (int off = 32; off > 0; off >>= 1) {
    s1 += __shfl_xor(s1, off);
    s2 += __shfl_xor(s2, off);
  }
  float rq = rsqrtf(s1 * (1.0f / 128.0f) + EPS);
  float rk = rsqrtf(s2 * (1.0f / 128.0f) + EPS);
  float w0 = q_ln_w[d0], w1 = q_ln_w[d0 + 1];
  float u0 = k_ln_w[d0], u1 = k_ln_w[d0 + 1];
  float qn0 = q0 * rq * w0, qn1 = q1 * rq * w1;
  float kn0 = k0 * rk * u0, kn1 = k1 * rk * u1;
  // partners (d ^ 64)
  float qp0 = __shfl_xor(qn0, 32), qp1 = __shfl_xor(qn1, 32);
  float kp0 = __shfl_xor(kn0, 32), kp1 = __shfl_xor(kn1, 32);
  int i0 = d0 & 63;
  // 1/ROPE_BASE^(i/64) = 2^(-i*log2(6e5)/64); log2(600000)=19.194593
  float invf0 = exp2f((float)i0 * (-19.194593f / 64.0f));
  float invf1 = exp2f((float)(i0 + 1) * (-19.194593f / 64.0f));
  float pos = (float)positions[t];
  float a0 = pos * invf0, a1 = pos * invf1;
  float c0 = cosf(a0), sn0 = sinf(a0), c1 = cosf(a1), sn1 = sinf(a1);
  bool lo = lane < 32;
  float qr0 = lo ? (qn0 * c0 - qp0 * sn0) : (qn0 * c0 + qp0 * sn0);
  float qr1 = lo ? (qn1 * c1 - qp1 * sn1) : (qn1 * c1 + qp1 * sn1);
  float kr0 = lo ? (kn0 * c0 - kp0 * sn0) : (kn0 * c0 + kp0 * sn0);
  float kr1 = lo ? (kn1 * c1 - kp1 * sn1) : (kn1 * c1 + kp1 * sn1);
  *(unsigned*)(q_t + base) = pack2(f2bf(qr0 * SCALE), f2bf(qr1 * SCALE));
  *(unsigned*)(k_t + base) = pack2(f2bf(kr0), f2bf(kr1));
}

// ---------------- phase B: G[h][c][e][d] = sum_{t in chunk} V[t][e] K[t][d] ----
__global__ __launch_bounds__(256) void attn_phaseB(const u16* __restrict__ k_t,
                                                   const u16* __restrict__ v_t,
                                                   u16* __restrict__ G) {
  const int c = blockIdx.x, h = blockIdx.y;
  __shared__ u16 lV[128 * 72];
  __shared__ u16 lK[128 * 72];
  const int tid = threadIdx.x, wave = tid >> 6, lane = tid & 63;
  const int wm = (wave >> 1) * 64, wn = (wave & 1) * 64;
  const int lr = lane & 15, lg = lane >> 4;
  f32x4 acc[4][4];
  #pragma unroll
  for (int i = 0; i < 4; i++)
    #pragma unroll
    for (int j = 0; j < 4; j++) acc[i][j] = (f32x4){0.f, 0.f, 0.f, 0.f};

  const int t0 = (tid >> 4) * 4;            // 0..60, 4 rows per thread
  const int ds = (tid & 15) * 8;            // d-segment of 8
  for (int h2 = 0; h2 < 2; h2++) {
    __syncthreads();
    const u16* vsrc = v_t + ((size_t)h * T_SEQ + c * 128 + h2 * 64 + t0) * HD + ds;
    const u16* ksrc = k_t + ((size_t)h * T_SEQ + c * 128 + h2 * 64 + t0) * HD + ds;
    int4 rv[4], rk[4];
    #pragma unroll
    for (int r = 0; r < 4; r++) {
      rv[r] = *(const int4*)(vsrc + r * HD);
      rk[r] = *(const int4*)(ksrc + r * HD);
    }
    const u16* v0 = (const u16*)&rv[0]; const u16* v1 = (const u16*)&rv[1];
    const u16* v2 = (const u16*)&rv[2]; const u16* v3 = (const u16*)&rv[3];
    const u16* K0 = (const u16*)&rk[0]; const u16* K1 = (const u16*)&rk[1];
    const u16* K2 = (const u16*)&rk[2]; const u16* K3 = (const u16*)&rk[3];
    #pragma unroll
    for (int j = 0; j < 8; j++) {
      uint2 wv, wk;
      wv.x = pack2(v0[j], v1[j]); wv.y = pack2(v2[j], v3[j]);
      wk.x = pack2(K0[j], K1[j]); wk.y = pack2(K2[j], K3[j]);
      *(uint2*)&lV[(ds + j) * 72 + t0] = wv;
      *(uint2*)&lK[(ds + j) * 72 + t0] = wk;
    }
    __syncthreads();
    #pragma unroll
    for (int kk = 0; kk < 64; kk += 32) {
      short8 af[4], bfr[4];
      #pragma unroll
      for (int i = 0; i < 4; i++)
        af[i] = *(const short8*)&lV[(wm + i * 16 + lr) * 72 + kk + lg * 8];
      #pragma unroll
      for (int j = 0; j < 4; j++)
        bfr[j] = *(const short8*)&lK[(wn + j * 16 + lr) * 72 + kk + lg * 8];
      #pragma unroll
      for (int i = 0; i < 4; i++)
        #pragma unroll
        for (int j = 0; j < 4; j++)
          acc[i][j] = mfma16(af[i], bfr[j], acc[i][j]);
    }
  }
  u16* Gp = G + ((size_t)h * NCH + c) * 16384;
  #pragma unroll
  for (int i = 0; i < 4; i++)
    #pragma unroll
    for (int j = 0; j < 4; j++)
      #pragma unroll
      for (int r = 0; r < 4; r++)
        Gp[(wm + i * 16 + lg * 4 + r) * 128 + wn + j * 16 + lr] = f2bf(acc[i][j][r]);
}

// exclusive prefix over chunk axis, bf16 storage / fp32 accumulator, in place
__global__ __launch_bounds__(256) void prefix_S(u16* __restrict__ G) {
  int idx = blockIdx.x * 256 + threadIdx.x;   // 65536 threads over 16*4096 quads
  int h = idx >> 12;
  int e4 = (idx & 4095) * 4;
  float run0 = 0.f, run1 = 0.f, run2 = 0.f, run3 = 0.f;
  size_t base = (size_t)h * NCH * 16384 + e4;
  for (int c = 0; c < NCH; c++) {
    uint2 g = *(uint2*)&G[base + (size_t)c * 16384];
    float a0 = bf2f((u16)g.x), a1 = bf2f((u16)(g.x >> 16));
    float a2 = bf2f((u16)g.y), a3 = bf2f((u16)(g.y >> 16));
    uint2 o;
    o.x = pack2(f2bf(run0), f2bf(run1));
    o.y = pack2(f2bf(run2), f2bf(run3));
    *(uint2*)&G[base + (size_t)c * 16384] = o;
    run0 += a0; run1 += a1; run2 += a2; run3 += a3;
  }
}

// ---------------- phase C: O = tril(Q K^T) V + Q S ----------------
// writes O head-major IN PLACE into the G tile this block consumed
__global__ __launch_bounds__(256) void attn_phaseC(const u16* __restrict__ q_t,
                                                   const u16* __restrict__ k_t,
                                                   const u16* __restrict__ v_t,
                                                   const u16* __restrict__ G,
                                                   u16* __restrict__ o_hm) {
  const int c = blockIdx.x, h = blockIdx.y;
  __shared__ u16 lP[128 * 136];
  __shared__ u16 lV[128 * 72];
  const int tid = threadIdx.x, wave = tid >> 6, lane = tid & 63;
  const int wm = wave * 32;          // 4x1 wave layout, 32 rows each
  const int lr = lane & 15, lg = lane >> 4;

  f32x4 acc1[2][8], acc2[2][8];
  #pragma unroll
  for (int i = 0; i < 2; i++)
    #pragma unroll
    for (int j = 0; j < 8; j++) {
      acc1[i][j] = (f32x4){0.f, 0.f, 0.f, 0.f};
      acc2[i][j] = (f32x4){0.f, 0.f, 0.f, 0.f};
    }

  const u16* Sp = G + ((size_t)h * NCH + c) * 16384;
  const u16* qbase = q_t + ((size_t)h * T_SEQ + c * 128) * HD;
  const u16* kbase = k_t + ((size_t)h * T_SEQ + c * 128) * HD;

  #pragma unroll
  for (int kk = 0; kk < 128; kk += 32) {
    short8 af[2];
    #pragma unroll
    for (int i = 0; i < 2; i++)
      af[i] = *(const short8*)(qbase + (wm + i * 16 + lr) * HD + kk + lg * 8);
    #pragma unroll
    for (int j = 0; j < 8; j++) {
      short8 bK = *(const short8*)(kbase + (j * 16 + lr) * HD + kk + lg * 8);
      short8 bS = *(const short8*)(Sp + (j * 16 + lr) * 128 + kk + lg * 8);
      #pragma unroll
      for (int i = 0; i < 2; i++) {
        acc1[i][j] = mfma16(af[i], bK, acc1[i][j]);   // scores
        acc2[i][j] = mfma16(af[i], bS, acc2[i][j]);   // Q @ S
      }
    }
  }
  // mask scores (tril) and park P in LDS (bf16, row-major over s)
  #pragma unroll
  for (int i = 0; i < 2; i++)
    #pragma unroll
    for (int j = 0; j < 8; j++)
      #pragma unroll
      for (int r = 0; r < 4; r++) {
        int row = wm + i * 16 + lg * 4 + r;
        int col = j * 16 + lr;
        float v = (col <= row) ? acc1[i][j][r] : 0.0f;
        lP[row * 136 + col] = f2bf(v);
      }

  const int t0 = (tid >> 4) * 4;            // register-transpose staging for V
  const int ds = (tid & 15) * 8;
  for (int sh2 = 0; sh2 < 2; sh2++) {
    __syncthreads();
    const u16* vsrc = v_t + ((size_t)h * T_SEQ + c * 128 + sh2 * 64 + t0) * HD + ds;
    int4 rv[4];
    #pragma unroll
    for (int r = 0; r < 4; r++) rv[r] = *(const int4*)(vsrc + r * HD);
    const u16* v0 = (const u16*)&rv[0]; const u16* v1 = (const u16*)&rv[1];
    const u16* v2 = (const u16*)&rv[2]; const u16* v3 = (const u16*)&rv[3];
    #pragma unroll
    for (int j = 0; j < 8; j++) {
      uint2 wv;
      wv.x = pack2(v0[j], v1[j]); wv.y = pack2(v2[j], v3[j]);
      *(uint2*)&lV[(ds + j) * 72 + t0] = wv;
    }
    __syncthreads();
    #pragma unroll
    for (int kk = 0; kk < 64; kk += 32) {
      short8 af[2];
      #pragma unroll
      for (int i = 0; i < 2; i++)
        af[i] = *(const short8*)&lP[(wm + i * 16 + lr) * 136 + sh2 * 64 + kk + lg * 8];
      #pragma unroll
      for (int j = 0; j < 8; j++) {
        short8 bV = *(const short8*)&lV[(j * 16 + lr) * 72 + kk + lg * 8];
        #pragma unroll
        for (int i = 0; i < 2; i++)
          acc2[i][j] = mfma16(af[i], bV, acc2[i][j]);
      }
    }
  }
  u16* op = o_hm + ((size_t)h * NCH + c) * 16384;
  #pragma unroll
  for (int i = 0; i < 2; i++)
    #pragma unroll
    for (int j = 0; j < 8; j++)
      #pragma unroll
      for (int r = 0; r < 4; r++) {
        int row = wm + i * 16 + lg * 4 + r;
        int e = j * 16 + lr;
        op[row * 128 + e] = f2bf(acc2[i][j][r]);
      }
}

// ---------------- gated rmsnorm: gated = sigmoid(gate) * rmsnorm(o) ----------------
__global__ __launch_bounds__(256) void gated_kernel(const u16* __restrict__ o_hm,
                                                    const u16* __restrict__ gate_bf,
                                                    const float* __restrict__ g_norm_w,
                                                    u16* __restrict__ gated_bf) {
  const int t = blockIdx.x, tid = threadIdx.x;
  const int h = tid >> 4, e0 = (tid & 15) * 8;
  const int c = t >> 7, row = t & 127;
  short8 ov = *(const short8*)(o_hm + (((size_t)h * NCH + c) * 128 + row) * 128 + e0);
  const u16* ovp = (const u16*)&ov;
  float vals[8], ss = 0.f;
  #pragma unroll
  for (int j = 0; j < 8; j++) {
    float v = bf2f(ovp[j]);
    vals[j] = v;
    ss += v * v;
  }
  #pragma unroll
  for (int off = 32; off > 0; off >>= 1) ss += __shfl_xor(ss, off);
  __shared__ float sh[4];
  if ((tid & 63) == 0) sh[tid >> 6] = ss;
  __syncthreads();
  ss = sh[0] + sh[1] + sh[2] + sh[3];
  float r = rsqrtf(ss * (1.0f / 2048.0f) + EPS);
  short8 gv = *(const short8*)(gate_bf + (size_t)t * 2048 + tid * 8);
  const u16* gvp = (const u16*)&gv;
  float4 w0 = *(const float4*)(g_norm_w + tid * 8);
  float4 w1 = *(const float4*)(g_norm_w + tid * 8 + 4);
  float wv[8] = {w0.x, w0.y, w0.z, w0.w, w1.x, w1.y, w1.z, w1.w};
  alignas(16) u16 outu[8];
  #pragma unroll
  for (int j = 0; j < 8; j++) {
    float normed = vals[j] * r * wv[j];
    float g = bf2f(gvp[j]);
    float sg = 1.0f / (1.0f + __expf(-g));
    outu[j] = f2bf(normed * sg);
  }
  *(int4*)(gated_bf + (size_t)t * 2048 + tid * 8) = *(const int4*)outu;
}

// ---------------- launch ----------------
extern "C" void kernel_launch(void* const* d_in, const int* in_sizes, int n_in,
                              void* d_out, int out_size, void* d_ws, size_t ws_size,
                              hipStream_t stream) {
  const float* x = (const float*)d_in[0];
  const int* positions = (const int*)d_in[1];
  const float* Wqkv = (const float*)d_in[2];
  const float* q_ln_w = (const float*)d_in[3];
  const float* k_ln_w = (const float*)d_in[4];
  const float* Wg = (const float*)d_in[5];
  const float* g_norm_w = (const float*)d_in[6];
  const float* Wo = (const float*)d_in[7];
  float* out = (float*)d_out;

  // Regions (32 MiB each unless noted), aliased by lifetime:
  //  R0 [0,32M):      WqkvT(25.2M) -> G -> o_hm (in-place per-block)
  //  R1 [32M,40M):    WgT (8M)
  //  R2 [40M,72M):    q_t -> gated
  //  R3 [72M,104M):   k_t -> gate_bf
  //  R4 [104M,136M):  v_t -> WoT (8M)
  //  R5 [136M,168M):  x_bf (alive the whole pipeline; no recast)
  char* ws = (char*)d_ws;
  const size_t M32 = (size_t)32 * 1024 * 1024;
  u16* WqkvT   = (u16*)ws;
  u16* G       = (u16*)ws;
  u16* WgT     = (u16*)(ws + M32);
  u16* q_t     = (u16*)(ws + M32 + 8388608);
  u16* gated   = q_t;
  u16* k_t     = (u16*)(ws + M32 + 8388608 + M32);
  u16* gate_bf = k_t;
  u16* v_t     = (u16*)(ws + M32 + 8388608 + 2 * M32);
  u16* WoT     = v_t;
  u16* x_bf    = (u16*)(ws + M32 + 8388608 + 3 * M32);
  const size_t needed = M32 + 8388608 + 4 * M32;   // 176,160,768
  if (ws_size < needed) return;

  cast_f32_bf16<<<8192, 256, 0, stream>>>(x, x_bf, (long)8192 * 2048);
  transpose_cast<<<dim3(96, 32), dim3(64, 4), 0, stream>>>(Wqkv, WqkvT, 2048, 6144);
  transpose_cast<<<dim3(32, 32), dim3(64, 4), 0, stream>>>(Wg, WgT, 2048, 2048);

  gemm256<2><<<dim3(24, 32), 512, 0, stream>>>(x_bf, WqkvT, 6144, nullptr, nullptr, q_t, k_t, v_t);

  qk_prep<<<dim3(8192, 4), 256, 0, stream>>>(q_t, k_t, positions, q_ln_w, k_ln_w);

  attn_phaseB<<<dim3(64, 16), 256, 0, stream>>>(k_t, v_t, G);
  prefix_S<<<256, 256, 0, stream>>>(G);
  attn_phaseC<<<dim3(64, 16), 256, 0, stream>>>(q_t, k_t, v_t, G, /*o_hm=*/G);

  // x_bf still alive -> gate GEMM directly (no recast); gate_bf overlays dead k_t
  gemm256<1><<<dim3(8, 32), 512, 0, stream>>>(x_bf, WgT, 2048, nullptr, gate_bf, nullptr, nullptr, nullptr);
  gated_kernel<<<8192, 256, 0, stream>>>(G, gate_bf, g_norm_w, gated);

  transpose_cast<<<dim3(32, 32), dim3(64, 4), 0, stream>>>(Wo, WoT, 2048, 2048);
  gemm256<0><<<dim3(8, 32), 512, 0, stream>>>(gated, WoT, 2048, out, nullptr, nullptr, nullptr, nullptr);
}